// Round 1
// baseline (1320.380 us; speedup 1.0000x reference)
//
#include <hip/hip_runtime.h>
#include <math.h>

constexpr int Bk = 32;    // K neighbors
constexpr int Dd = 128;   // feature dim
constexpr int Hh = 4;     // heads
constexpr int NB = 16;    // batch elements per block

__global__ __launch_bounds__(256, 4)
void gtn_kernel(const float* __restrict__ tgt,
                const float* __restrict__ neigh,
                const float* __restrict__ Wh,
                const float* __restrict__ bh,
                const float* __restrict__ Wp,
                const float* __restrict__ bp,
                float* __restrict__ out)
{
    __shared__ __align__(16) float wt[Hh][Dd];      // W_heads[:, :D]
    __shared__ __align__(16) float wn[Hh][Dd];      // W_heads[:, D:]
    __shared__ __align__(16) float4 att4[4][Bk];    // per-wave attention
    __shared__ __align__(16) float hcat[NB][516];   // concat heads, padded stride

    const int tid = threadIdx.x;
    const int w   = tid >> 6;    // wave 0..3
    const int l   = tid & 63;    // lane 0..63
    const int bbase = blockIdx.x * NB;

    // ---- stage W_heads into LDS (1024 floats = 256 x float4) ----
    {
        float4 v = ((const float4*)Wh)[tid];
        int h = tid >> 6;          // 64 float4 per head row (256 floats)
        int c = tid & 63;
        if (c < 32) ((float4*)&wt[h][0])[c]      = v;
        else        ((float4*)&wn[h][0])[c - 32] = v;
    }
    __syncthreads();

    // ---- Phase A: each wave computes h for 4 batch elements ----
    const int k    = l & 31;
    const int half = l >> 5;

    for (int i = 0; i < NB / 4; ++i) {
        const int bb = w * 4 + i;       // 0..15 within block
        const int b  = bbase + bb;

        // target dot per head (full 64-lane reduce)
        float tq[Hh];
        {
            const float2 tv = ((const float2*)tgt)[(size_t)b * 64 + l];
            #pragma unroll
            for (int h = 0; h < Hh; ++h) {
                float2 wv = ((const float2*)&wt[h][0])[l];
                float p = tv.x * wv.x + tv.y * wv.y;
                #pragma unroll
                for (int m = 1; m < 64; m <<= 1)
                    p += __shfl_xor(p, m);
                tq[h] = p;
            }
        }

        // neighbor scores: lane covers (k, half-row of 64 d)
        float accS[Hh] = {0.f, 0.f, 0.f, 0.f};
        const float4* nrow = (const float4*)(neigh + ((size_t)(b * Bk + k)) * Dd + half * 64);
        #pragma unroll 4
        for (int j = 0; j < 16; ++j) {
            float4 v = nrow[j];
            #pragma unroll
            for (int h = 0; h < Hh; ++h) {
                float4 wv = ((const float4*)&wn[h][0])[half * 16 + j];
                accS[h] += v.x * wv.x + v.y * wv.y + v.z * wv.z + v.w * wv.w;
            }
        }

        // combine halves, add tgt dot + bias, relu
        float s[Hh];
        #pragma unroll
        for (int h = 0; h < Hh; ++h) {
            float d0 = accS[h] + __shfl_xor(accS[h], 32);
            float sc = d0 + tq[h] + bh[h];
            s[h] = fmaxf(sc, 0.f);
        }

        // softmax over 32 k (halves hold identical values)
        float attv[Hh];
        #pragma unroll
        for (int h = 0; h < Hh; ++h) {
            float m = s[h];
            #pragma unroll
            for (int msk = 1; msk < 32; msk <<= 1)
                m = fmaxf(m, __shfl_xor(m, msk));
            float e = __expf(s[h] - m);
            float sum = e;
            #pragma unroll
            for (int msk = 1; msk < 32; msk <<= 1)
                sum += __shfl_xor(sum, msk);
            attv[h] = e / sum;
        }
        if (l < 32) {
            att4[w][k] = make_float4(attv[0], attv[1], attv[2], attv[3]);
        }
        // within-wave LDS dependency: compiler inserts lgkmcnt wait

        // aggregate: lane owns d = 2l, 2l+1
        float ax[Hh] = {0.f, 0.f, 0.f, 0.f};
        float ay[Hh] = {0.f, 0.f, 0.f, 0.f};
        const float2* nb2 = (const float2*)(neigh + (size_t)b * Bk * Dd);
        #pragma unroll 4
        for (int kk = 0; kk < Bk; ++kk) {
            float2 nv = nb2[kk * 64 + l];
            float4 a  = att4[w][kk];
            ax[0] += a.x * nv.x;  ay[0] += a.x * nv.y;
            ax[1] += a.y * nv.x;  ay[1] += a.y * nv.y;
            ax[2] += a.z * nv.x;  ay[2] += a.z * nv.y;
            ax[3] += a.w * nv.x;  ay[3] += a.w * nv.y;
        }
        #pragma unroll
        for (int h = 0; h < Hh; ++h) {
            ((float2*)&hcat[bb][h * 128])[l] = make_float2(ax[h], ay[h]);
        }
    }
    __syncthreads();

    // ---- Projection: out[b, d] = sum_j hcat[b][j] * Wp[d][j] + bp[d] ----
    {
        const int d     = tid & 127;
        const int halfb = tid >> 7;   // 0..1 -> which 8 b's
        float acc[8] = {0.f, 0.f, 0.f, 0.f, 0.f, 0.f, 0.f, 0.f};
        const float4* wrow = (const float4*)(Wp + (size_t)d * 512);
        #pragma unroll 2
        for (int j4 = 0; j4 < 128; ++j4) {
            float4 wv = wrow[j4];
            #pragma unroll
            for (int q = 0; q < 8; ++q) {
                float4 h4 = ((const float4*)&hcat[halfb * 8 + q][0])[j4];
                acc[q] += h4.x * wv.x + h4.y * wv.y + h4.z * wv.z + h4.w * wv.w;
            }
        }
        float bpv = bp[d];
        #pragma unroll
        for (int q = 0; q < 8; ++q) {
            out[(size_t)(bbase + halfb * 8 + q) * 128 + d] = acc[q] + bpv;
        }
    }
}

extern "C" void kernel_launch(void* const* d_in, const int* in_sizes, int n_in,
                              void* d_out, int out_size, void* d_ws, size_t ws_size,
                              hipStream_t stream) {
    const float* tgt   = (const float*)d_in[0];
    const float* neigh = (const float*)d_in[1];
    const float* Wh    = (const float*)d_in[2];
    const float* bhv   = (const float*)d_in[3];
    const float* Wp    = (const float*)d_in[4];
    const float* bpv   = (const float*)d_in[5];
    float* out = (float*)d_out;

    const int nblocks = 50000 / NB;   // 3125, exact
    gtn_kernel<<<nblocks, 256, 0, stream>>>(tgt, neigh, Wh, bhv, Wp, bpv, out);
}